// Round 14
// baseline (331.515 us; speedup 1.0000x reference)
//
#include <hip/hip_runtime.h>
#include <hip/hip_bf16.h>
#include <stdint.h>

#define N_SUP 16384
#define DIM   1024
#define NLV   4
#define NCLS  64
#define NFUSE 4096          // 4 levels x 1024

typedef __bf16 bf16x8 __attribute__((ext_vector_type(8)));
typedef __bf16 bf16x4 __attribute__((ext_vector_type(4)));
typedef float  f32x4  __attribute__((ext_vector_type(4)));

#define GLOAD_LDS16(g, l) \
    __builtin_amdgcn_global_load_lds((const __attribute__((address_space(1))) void*)(g), \
                                     (__attribute__((address_space(3))) void*)(l), 16, 0, 0)

// ---- class histogram, LDS-aggregated ----
__global__ __launch_bounds__(256) void k_count(const int* __restrict__ labels,
                                               int* __restrict__ gcnt) {
    __shared__ int hist[NCLS];
    int tid = threadIdx.x;
    if (tid < NCLS) hist[tid] = 0;
    __syncthreads();
    atomicAdd(&hist[labels[blockIdx.x * 256 + tid]], 1);
    __syncthreads();
    if (tid < NCLS && hist[tid] > 0) atomicAdd(&gcnt[tid], hist[tid]);
}

// ---- tiny scan: gstart, gcur, counts_f ----
__global__ __launch_bounds__(64) void k_scan(const int* __restrict__ gcnt,
                                             int* __restrict__ gstart,
                                             int* __restrict__ gcur,
                                             float* __restrict__ counts_f) {
    int tid = threadIdx.x;
    __shared__ int s[NCLS];
    s[tid] = gcnt[tid];
    __syncthreads();
    if (tid == 0) {
        int run = 0;
        for (int c = 0; c < NCLS; ++c) { int v = s[c]; s[c] = run; run += v; }
    }
    __syncthreads();
    gstart[tid] = s[tid];
    gcur[tid] = s[tid];
    counts_f[tid] = fmaxf((float)gcnt[tid], 1.0f);
}

// ---- scatter, LDS-aggregated; emits inv AND rowlist ----
__global__ __launch_bounds__(256) void k_scatter(const int* __restrict__ labels,
                                                 int* __restrict__ gcur,
                                                 int* __restrict__ inv,
                                                 int* __restrict__ rowlist) {
    __shared__ int hist[NCLS];
    __shared__ int base[NCLS];
    int tid = threadIdx.x;
    int r = blockIdx.x * 256 + tid;
    if (tid < NCLS) hist[tid] = 0;
    __syncthreads();
    int lab = labels[r];
    int lrank = atomicAdd(&hist[lab], 1);
    __syncthreads();
    if (tid < NCLS && hist[tid] > 0) base[tid] = atomicAdd(&gcur[tid], hist[tid]);
    __syncthreads();
    int pos = base[lab] + lrank;
    inv[r] = pos;
    rowlist[pos] = r;
}

// ==== mega prep dispatch: conv_feat (16384) | wt+eff (1024) | rawsum gather (256) ====
__global__ __launch_bounds__(256) void k_prep(const float* __restrict__ feat,
                                              const int* __restrict__ inv,
                                              const int* __restrict__ rowlist,
                                              const float* __restrict__ an_w1,
                                              const float* __restrict__ an_b1,
                                              const float* __restrict__ lvl_emb,
                                              const int* __restrict__ gstart,
                                              const int* __restrict__ gcnt,
                                              __bf16* __restrict__ featb,
                                              __bf16* __restrict__ w1t,
                                              float* __restrict__ eff,
                                              float* __restrict__ rawsum,
                                              float* __restrict__ tcsum) {
    __shared__ float tile[64][65];
    const int lin = blockIdx.x;
    const int tid = threadIdx.x;
    if (lin < 16384) {
        // conv + permute: featb[inv[r]] = bf16(feat[r])
        int r = lin;
        int dr = inv[r];
        float4 v = *(const float4*)(feat + (size_t)r * DIM + tid * 4);
        union { __bf16 b[4]; uint64_t u; } pk;
        pk.b[0] = (__bf16)v.x; pk.b[1] = (__bf16)v.y;
        pk.b[2] = (__bf16)v.z; pk.b[3] = (__bf16)v.w;
        *(uint64_t*)(featb + (size_t)dr * DIM + tid * 4) = pk.u;
    } else if (lin < 16384 + 1024) {
        // weight transpose + eff_b1
        int idx = lin - 16384;
        int m = idx >> 8;
        int rem = idx & 255;
        int k0 = (rem & 15) * 64, n0 = (rem >> 4) * 64;
        const float* src = an_w1 + (size_t)m * 1025 * 1024;
        __bf16* dst = w1t + (size_t)m * 1024 * 1024;
        int j = tid & 63, i0 = tid >> 6;
        #pragma unroll
        for (int ii = 0; ii < 16; ++ii) {
            int i = i0 + ii * 4;
            tile[i][j] = src[(size_t)(k0 + i) * 1024 + n0 + j];
        }
        __syncthreads();
        #pragma unroll
        for (int ii = 0; ii < 16; ++ii) {
            int i = i0 + ii * 4;
            dst[(size_t)(n0 + i) * 1024 + k0 + j] = (__bf16)tile[j][i];
        }
        if ((rem >> 4) == 0 && tid < 64) {
            int jj = k0 + tid;
            eff[m * 1024 + jj] = an_b1[m * 1024 + jj]
                               + lvl_emb[m] * src[(size_t)1024 * 1024 + jj];
        }
    } else {
        // rawsum gather from f32 feat via rowlist (+ column totals)
        int idx = lin - 17408;
        int c = idx >> 2;
        int col = (idx & 3) * 256 + tid;
        int st = gstart[c], n = gcnt[c];
        float acc = 0.f;
        int i = 0;
        for (; i + 8 <= n; i += 8) {
            int r[8];
            #pragma unroll
            for (int j = 0; j < 8; ++j) r[j] = rowlist[st + i + j];
            float v[8];
            #pragma unroll
            for (int j = 0; j < 8; ++j) v[j] = feat[(size_t)r[j] * DIM + col];
            #pragma unroll
            for (int j = 0; j < 8; ++j) acc += v[j];
        }
        for (; i < n; ++i) acc += feat[(size_t)rowlist[st + i] * DIM + col];
        rawsum[(size_t)c * DIM + col] = acc;
        atomicAdd(&tcsum[col], acc);
    }
}

// ==================== 256x256 balanced 4-phase bf16 MFMA GEMM (R9 core) ====
// 1D grid: blocks 0..1023 = GEMM tiles; blocks 1024..1039 = gemv1 (split-K head).
__global__ __launch_bounds__(512, 2) void k_gemm256(const __bf16* __restrict__ A,
                                                    const __bf16* __restrict__ Bt,
                                                    const float* __restrict__ bias,
                                                    __bf16* __restrict__ C,
                                                    const float* __restrict__ tc,
                                                    const float* __restrict__ sp_w1,
                                                    float* __restrict__ hpre,
                                                    int K, int Nn, int NT) {
    const int lin = blockIdx.x;
    if (lin >= 1024) {
        // ---- gemv1: hpre[j] += sum_k tc[k]/N * sp_w1[k][j] over one 64-chunk ----
        __shared__ float tcs[64];
        int tid = threadIdx.x;
        int kb = (lin - 1024) * 64;
        if (tid < 64) tcs[tid] = tc[kb + tid] * (1.0f / N_SUP);
        __syncthreads();
        float acc = 0.f;
        #pragma unroll 8
        for (int k = 0; k < 64; ++k)
            acc += tcs[k] * sp_w1[(size_t)(kb + k) * 512 + tid];
        atomicAdd(&hpre[tid], acc);
        return;
    }
    __shared__ __bf16 lds[65536];   // [buf][A|B][half][2 x 64rows][64]
    const int tid = threadIdx.x;
    const int w   = tid >> 6;
    const int l   = tid & 63;
    const int wr  = w >> 2;
    const int wc  = w & 3;
    const int am  = l & 15;
    const int kg  = l >> 4;
    const size_t bm = (size_t)(lin & 63) * 256;
    const size_t bn = (size_t)(lin >> 6) * 256;

    const int srow = w * 8 + (l >> 3);
    const int scol = ((l & 7) ^ (l >> 3)) * 8;     // pre-swizzled source col
    const __bf16* gA[2][2]; const __bf16* gB[2][2];
    #pragma unroll
    for (int h = 0; h < 2; ++h)
        #pragma unroll
        for (int p = 0; p < 2; ++p) {
            gA[h][p] = A  + (bm + h * 128 + p * 64 + srow) * (size_t)K + scol;
            gB[h][p] = Bt + (bn + h * 128 + p * 64 + srow) * (size_t)K + scol;
        }

    f32x4 acc[8][4] = {};
    bf16x8 ax[4][2], ay[4][2], bx[2][2], by[2][2];

    // prologue: stage tile 0 (8 chunks), drain, read ax(0)
    #pragma unroll
    for (int h = 0; h < 2; ++h)
        #pragma unroll
        for (int p = 0; p < 2; ++p) {
            GLOAD_LDS16(gA[h][p], lds + h * 8192 + p * 4096 + w * 512);
            GLOAD_LDS16(gB[h][p], lds + 16384 + h * 8192 + p * 4096 + w * 512);
        }
    asm volatile("s_waitcnt vmcnt(0)" ::: "memory");
    __builtin_amdgcn_s_barrier();

    const int swzr = (am & 7) * 8;
    const int ko0 = (kg * 8) ^ swzr;
    const int ko1 = (32 + kg * 8) ^ swzr;
    {
        const __bf16* pa0 = lds + wr * 8192;
        #pragma unroll
        for (int i = 0; i < 4; ++i) {
            ax[i][0] = *(const bf16x8*)(pa0 + (i * 16 + am) * 64 + ko0);
            ax[i][1] = *(const bf16x8*)(pa0 + (i * 16 + am) * 64 + ko1);
        }
    }

#define MFMAQ(qm, qn, AF, BF) \
    __builtin_amdgcn_s_setprio(1); \
    _Pragma("unroll") \
    for (int i_ = 0; i_ < 4; ++i_) \
        _Pragma("unroll") \
        for (int j_ = 0; j_ < 2; ++j_) \
            _Pragma("unroll") \
            for (int k_ = 0; k_ < 2; ++k_) \
                acc[(qm) * 4 + i_][(qn) * 2 + j_] = __builtin_amdgcn_mfma_f32_16x16x32_bf16( \
                    AF[i_][k_], BF[j_][k_], acc[(qm) * 4 + i_][(qn) * 2 + j_], 0, 0, 0); \
    __builtin_amdgcn_s_setprio(0);

    for (int t = 0; t < NT; ++t) {
        const int cb = (t & 1) * 32768;
        const int nb = cb ^ 32768;
        const int tn = (t + 1) * 64;
        const bool more = (t + 1 < NT);
        const __bf16* pa  = lds + cb + wr * 8192;
        const __bf16* pan = lds + nb + wr * 8192;
        const __bf16* pb  = lds + cb + 16384 + (wc >> 1) * 8192 + (wc & 1) * 4096;

        // ---- ph0: issue Ap0(t+1); drain tile t; read bx(4)+ay0(2); MFMA q0 ----
        if (more) {
            GLOAD_LDS16(gA[0][0] + tn, lds + nb + 0 * 4096 + w * 512);
            GLOAD_LDS16(gA[1][0] + tn, lds + nb + 8192 + 0 * 4096 + w * 512);
            asm volatile("s_waitcnt vmcnt(2)" ::: "memory");
        } else {
            asm volatile("s_waitcnt vmcnt(0)" ::: "memory");
        }
        __builtin_amdgcn_s_barrier();
        #pragma unroll
        for (int j = 0; j < 2; ++j) {
            bx[j][0] = *(const bf16x8*)(pb + (j * 16 + am) * 64 + ko0);
            bx[j][1] = *(const bf16x8*)(pb + (j * 16 + am) * 64 + ko1);
        }
        ay[0][0] = *(const bf16x8*)(pa + ((4 + 0) * 16 + am) * 64 + ko0);
        ay[0][1] = *(const bf16x8*)(pa + ((4 + 0) * 16 + am) * 64 + ko1);
        MFMAQ(0, 0, ax, bx)

        // ---- ph1: issue Ap1(t+1); read by(4)+ay1(2); MFMA q1 ----
        if (more) {
            GLOAD_LDS16(gA[0][1] + tn, lds + nb + 1 * 4096 + w * 512);
            GLOAD_LDS16(gA[1][1] + tn, lds + nb + 8192 + 1 * 4096 + w * 512);
        }
        __builtin_amdgcn_s_barrier();
        #pragma unroll
        for (int j = 0; j < 2; ++j) {
            by[j][0] = *(const bf16x8*)(pb + ((2 + j) * 16 + am) * 64 + ko0);
            by[j][1] = *(const bf16x8*)(pb + ((2 + j) * 16 + am) * 64 + ko1);
        }
        ay[1][0] = *(const bf16x8*)(pa + ((4 + 1) * 16 + am) * 64 + ko0);
        ay[1][1] = *(const bf16x8*)(pa + ((4 + 1) * 16 + am) * 64 + ko1);
        MFMAQ(0, 1, ax, by)

        // ---- ph2: issue B0(t+1); drain Ap0(t+1); read ay23(4)+ax'01(4); MFMA q2 ----
        if (more) {
            GLOAD_LDS16(gB[0][0] + tn, lds + nb + 16384 + 0 * 4096 + w * 512);
            GLOAD_LDS16(gB[0][1] + tn, lds + nb + 16384 + 1 * 4096 + w * 512);
            asm volatile("s_waitcnt vmcnt(4)" ::: "memory");
        }
        __builtin_amdgcn_s_barrier();
        #pragma unroll
        for (int i = 2; i < 4; ++i) {
            ay[i][0] = *(const bf16x8*)(pa + ((4 + i) * 16 + am) * 64 + ko0);
            ay[i][1] = *(const bf16x8*)(pa + ((4 + i) * 16 + am) * 64 + ko1);
        }
        if (more) {
            #pragma unroll
            for (int i = 0; i < 2; ++i) {
                ax[i][0] = *(const bf16x8*)(pan + (i * 16 + am) * 64 + ko0);
                ax[i][1] = *(const bf16x8*)(pan + (i * 16 + am) * 64 + ko1);
            }
        }
        MFMAQ(1, 0, ay, bx)

        // ---- ph3: issue B1(t+1); read ax'23(4); MFMA q3 ----
        if (more) {
            GLOAD_LDS16(gB[1][0] + tn, lds + nb + 16384 + 8192 + 0 * 4096 + w * 512);
            GLOAD_LDS16(gB[1][1] + tn, lds + nb + 16384 + 8192 + 1 * 4096 + w * 512);
        }
        __builtin_amdgcn_s_barrier();
        if (more) {
            #pragma unroll
            for (int i = 2; i < 4; ++i) {
                ax[i][0] = *(const bf16x8*)(pan + (i * 16 + am) * 64 + ko0);
                ax[i][1] = *(const bf16x8*)(pan + (i * 16 + am) * 64 + ko1);
            }
        }
        MFMAQ(1, 1, ay, by)
    }
#undef MFMAQ

    const int rbase = kg * 4;    // C/D: col=lane&15, row=(lane>>4)*4+reg
    #pragma unroll
    for (int m = 0; m < 8; ++m) {
        const size_t row = bm + wr * 128 + m * 16 + rbase;
        #pragma unroll
        for (int n = 0; n < 4; ++n) {
            const int col = (int)bn + wc * 64 + n * 16 + am;
            const float bv = bias[col];
            #pragma unroll
            for (int r = 0; r < 4; ++r)
                C[(row + r) * (size_t)Nn + col] = (__bf16)(acc[m][n][r] + bv);
        }
    }
}

// ===== fused LN+ReLU+segment-sum, wave-per-row over SORTED hh =====
__global__ __launch_bounds__(256) void k_gather_ln(const __bf16* __restrict__ hh,
                                                   const float* __restrict__ an_g,
                                                   const float* __restrict__ an_be,
                                                   const int* __restrict__ gstart,
                                                   const int* __restrict__ gcnt,
                                                   float* __restrict__ gsum) {
    int c = blockIdx.x, lv = blockIdx.y, z = blockIdx.z;
    int tid = threadIdx.x;
    int wv = tid >> 6, lane = tid & 63;
    int colb = lane * 16;
    float g[16], b[16];
    #pragma unroll
    for (int j = 0; j < 16; j += 4) {
        float4 gv = *(const float4*)(an_g + lv * 1024 + colb + j);
        float4 bv = *(const float4*)(an_be + lv * 1024 + colb + j);
        g[j] = gv.x; g[j + 1] = gv.y; g[j + 2] = gv.z; g[j + 3] = gv.w;
        b[j] = bv.x; b[j + 1] = bv.y; b[j + 2] = bv.z; b[j + 3] = bv.w;
    }
    int st = gstart[c], n = gcnt[c];
    float acc[16] = {};
    for (int i = z * 4 + wv; i < n; i += 16) {
        const __bf16* row = hh + (size_t)(st + i) * NFUSE + lv * 1024 + colb;
        bf16x8 v0 = *(const bf16x8*)row;
        bf16x8 v1 = *(const bf16x8*)(row + 8);
        float x[16];
        #pragma unroll
        for (int j = 0; j < 8; ++j) { x[j] = (float)v0[j]; x[8 + j] = (float)v1[j]; }
        float s = 0.f, q = 0.f;
        #pragma unroll
        for (int j = 0; j < 16; ++j) { s += x[j]; q += x[j] * x[j]; }
        #pragma unroll
        for (int off = 1; off < 64; off <<= 1) {
            s += __shfl_xor(s, off);
            q += __shfl_xor(q, off);
        }
        float mu = s * (1.0f / DIM);
        float var = q * (1.0f / DIM) - mu * mu;
        float rstd = rsqrtf(var + 1e-5f);
        #pragma unroll
        for (int j = 0; j < 16; ++j) {
            float y = (x[j] - mu) * rstd * g[j] + b[j];
            acc[j] += y > 0.f ? y : 0.f;
        }
    }
    __shared__ float red[4][1024];
    #pragma unroll
    for (int j = 0; j < 16; ++j) red[wv][colb + j] = acc[j];
    __syncthreads();
    for (int col = tid; col < 1024; col += 256) {
        float v = red[0][col] + red[1][col] + red[2][col] + red[3][col];
        atomicAdd(&gsum[(size_t)c * NFUSE + lv * 1024 + col], v);
    }
}

// fusion_input build: packed part = proto_pre[l][c][d]/cnt[c] + b2[l][d]
__global__ __launch_bounds__(256) void k_build_fi(const float* __restrict__ proto_pre,
                                                  const float* __restrict__ an_b2,
                                                  const int* __restrict__ gcnt,
                                                  const float* __restrict__ counts_f,
                                                  const float* __restrict__ headf,
                                                  const int* __restrict__ headi,
                                                  float* __restrict__ fi) {
    int idx = blockIdx.x * 256 + threadIdx.x;
    if (idx >= 64 * 4160) return;
    int c = idx / 4160, col = idx % 4160;
    int kk = headi[0];
    float v = 0.f;
    if (col < kk * 1024) {
        int s = col >> 10, d = col & 1023;
        int l = headi[1 + s];
        if (gcnt[c] > 0)
            v = proto_pre[((size_t)l * NCLS + c) * DIM + d] / counts_f[c]
                + an_b2[(size_t)l * DIM + d];
    } else if (col < kk * 1024 + kk) {
        int s = col - kk * 1024;
        v = headf[headi[1 + s]];
    }
    fi[idx] = v;
}

// f32 split-K GEMM (64 x 1024 out), z-strided, atomic accumulate.
// abias != null: A element transformed as relu(a + abias[k]).
// do_head: blocks with z==4 run the head finisher (block (0,0,4) only).
__global__ __launch_bounds__(256) void k_fuse_gemm(const float* __restrict__ Abase, int lda, int az,
                                                   const float* __restrict__ Wbase, int wz,
                                                   float* __restrict__ outbase, int oz,
                                                   const float* __restrict__ abias,
                                                   int K, int do_head,
                                                   const float* __restrict__ hpre,
                                                   const float* __restrict__ sp_b1,
                                                   const float* __restrict__ sp_w2,
                                                   const float* __restrict__ sp_b2,
                                                   float* __restrict__ headf,
                                                   int* __restrict__ headi,
                                                   float* __restrict__ dout) {
    if (do_head && blockIdx.z == 4) {
        if (blockIdx.x != 0 || blockIdx.y != 0) return;
        __shared__ float hred[256];
        __shared__ float ha4[4];
        int tid = threadIdx.x;
        float hv0 = hpre[tid] + sp_b1[tid];
        hv0 = hv0 > 0.f ? hv0 : 0.f;
        float hv1 = hpre[tid + 256] + sp_b1[tid + 256];
        hv1 = hv1 > 0.f ? hv1 : 0.f;
        #pragma unroll
        for (int o = 0; o < 4; ++o) {
            hred[tid] = hv0 * sp_w2[tid * 4 + o] + hv1 * sp_w2[(tid + 256) * 4 + o];
            __syncthreads();
            for (int st = 128; st > 0; st >>= 1) {
                if (tid < st) hred[tid] += hred[tid + st];
                __syncthreads();
            }
            if (tid == 0) ha4[o] = 1.0f / (1.0f + expf(-(hred[0] + sp_b2[o])));
            __syncthreads();
        }
        if (tid == 0) {
            int kk = 0;
            int lvl[4] = {-1, -1, -1, -1};
            for (int l = 0; l < 4; ++l)
                if (ha4[l] > 0.1f) { lvl[kk] = l; kk++; }
            headi[0] = kk;
            for (int s = 0; s < 4; ++s) headi[1 + s] = lvl[s];
            for (int l = 0; l < 4; ++l) headf[l] = ha4[l];
        }
        if (tid < 4) {
            dout[65536 + tid] = ha4[tid];
            dout[65540 + tid] = ha4[tid] > 0.1f ? ha4[tid] : 0.f;
        }
        return;
    }
    const float* Afi = Abase + (size_t)blockIdx.z * az;
    const float* W   = Wbase + (size_t)blockIdx.z * wz;
    float* outp      = outbase + (size_t)blockIdx.z * oz;
    __shared__ float fi_lds[64][64];
    int tid = threadIdx.x;
    int tj = tid & 63, tg = tid >> 6;
    int jb = blockIdx.x;
    int k0 = blockIdx.y * 64;
    for (int i = tid; i < 64 * 64; i += 256) {
        int cc = i >> 6, kq = i & 63;
        float av = 0.f;
        if (k0 + kq < lda) {
            av = Afi[(size_t)cc * lda + k0 + kq];
            if (abias) {
                av += abias[k0 + kq];
                av = av > 0.f ? av : 0.f;
            }
        }
        fi_lds[cc][kq] = av;
    }
    __syncthreads();
    float acc[16] = {};
    #pragma unroll 4
    for (int kq = 0; kq < 64; ++kq) {
        int kg = k0 + kq;
        float wv = (kg < K) ? W[(size_t)kg * 1024 + jb * 64 + tj] : 0.f;
        #pragma unroll
        for (int cc = 0; cc < 16; ++cc)
            acc[cc] += fi_lds[tg * 16 + cc][kq] * wv;
    }
    #pragma unroll
    for (int cc = 0; cc < 16; ++cc)
        atomicAdd(&outp[(size_t)(tg * 16 + cc) * 1024 + jb * 64 + tj], acc[cc]);
}

__global__ __launch_bounds__(256) void k_final(const float* __restrict__ pre2,
                                               const float* __restrict__ fu_b2,
                                               const int* __restrict__ headi,
                                               const float* __restrict__ rawsum,
                                               const float* __restrict__ counts_f,
                                               float* __restrict__ dout) {
    int i = blockIdx.x * 256 + threadIdx.x;   // 65536
    int c = i >> 10, j = i & 1023;
    float v;
    if (headi[0] > 0) v = pre2[i] + fu_b2[j];
    else              v = rawsum[i] / counts_f[c];
    dout[i] = v;
}

extern "C" void kernel_launch(void* const* d_in, const int* in_sizes, int n_in,
                              void* d_out, int out_size, void* d_ws, size_t ws_size,
                              hipStream_t stream) {
    (void)in_sizes; (void)n_in; (void)out_size; (void)ws_size;
    const float* feat    = (const float*)d_in[0];
    const int*   labels  = (const int*)d_in[1];
    const float* sp_w1   = (const float*)d_in[2];
    const float* sp_b1   = (const float*)d_in[3];
    const float* sp_w2   = (const float*)d_in[4];
    const float* sp_b2   = (const float*)d_in[5];
    const float* lvl_emb = (const float*)d_in[6];
    const float* an_w1   = (const float*)d_in[7];
    const float* an_b1   = (const float*)d_in[8];
    const float* an_g    = (const float*)d_in[9];
    const float* an_be   = (const float*)d_in[10];
    const float* an_w2   = (const float*)d_in[11];
    const float* an_b2   = (const float*)d_in[12];
    const float* fu_w1   = (const float*)d_in[13];
    const float* fu_b1   = (const float*)d_in[14];
    const float* fu_w2   = (const float*)d_in[15];
    const float* fu_b2   = (const float*)d_in[16];
    float* dout = (float*)d_out;

    char* p = (char*)d_ws;
    auto alloc = [&](size_t b) { char* r = p; p += (b + 255) & ~(size_t)255; return r; };
    __bf16* featb = (__bf16*)alloc((size_t)N_SUP * DIM * 2);
    __bf16* w1t   = (__bf16*)alloc((size_t)NLV * DIM * DIM * 2);
    __bf16* hh    = (__bf16*)alloc((size_t)N_SUP * NFUSE * 2);
    float*  effb1 = (float*) alloc((size_t)NLV * DIM * 4);
    float*  fi    = (float*) alloc((size_t)64 * 4160 * 4);
    float*  rawsum  = (float*)alloc((size_t)NCLS * DIM * 4);
    int*    inv     = (int*)  alloc((size_t)N_SUP * 4);
    int*    rowlist = (int*)  alloc((size_t)N_SUP * 4);
    int*    gstart  = (int*)  alloc(NCLS * 4);
    int*    gcur    = (int*)  alloc(NCLS * 4);
    float*  counts_f= (float*)alloc(NCLS * 4);
    float*  headf   = (float*)alloc(4 * 4);
    int*    headi   = (int*)  alloc(8 * 4);
    char* z0 = p;
    int*    gcnt    = (int*)  alloc(NCLS * 4);
    float*  tc      = (float*)alloc(DIM * 4);
    float*  gsum    = (float*)alloc((size_t)NCLS * NFUSE * 4);
    float*  proto_pre = (float*)alloc((size_t)NLV * NCLS * DIM * 4);
    float*  h1pre   = (float*)alloc((size_t)NCLS * DIM * 4);
    float*  f2pre   = (float*)alloc((size_t)NCLS * DIM * 4);
    float*  hpre    = (float*)alloc(512 * 4);
    size_t zbytes = (size_t)(p - z0);
    hipMemsetAsync(z0, 0, zbytes, stream);

    k_count<<<N_SUP / 256, 256, 0, stream>>>(labels, gcnt);
    k_scan<<<1, 64, 0, stream>>>(gcnt, gstart, gcur, counts_f);
    k_scatter<<<N_SUP / 256, 256, 0, stream>>>(labels, gcur, inv, rowlist);
    // mega prep: conv (16384) | wt+eff (1024) | rawsum gather (256)
    k_prep<<<16384 + 1024 + 256, 256, 0, stream>>>(feat, inv, rowlist, an_w1, an_b1,
                                                   lvl_emb, gstart, gcnt,
                                                   featb, w1t, effb1, rawsum, tc);
    // fused 4-level GEMM1 + gemv1 tail blocks
    k_gemm256<<<1024 + 16, 512, 0, stream>>>(featb, w1t, effb1, hh,
                                             tc, sp_w1, hpre, DIM, NFUSE, DIM / 64);
    // fused LN+ReLU+segment-sum (contiguous class ranges)
    k_gather_ln<<<dim3(NCLS, NLV, 4), 256, 0, stream>>>(hh, an_g, an_be, gstart, gcnt, gsum);
    // proto_pre[l] = gsum[:, l*1024:+1024] @ an_w2[l]; z==4 runs head finisher
    k_fuse_gemm<<<dim3(16, 16, 5), 256, 0, stream>>>(gsum, NFUSE, 1024,
                                                     an_w2, 1024 * 1024,
                                                     proto_pre, NCLS * DIM, nullptr, 1024,
                                                     1, hpre, sp_b1, sp_w2, sp_b2,
                                                     headf, headi, dout);
    k_build_fi<<<(64 * 4160) / 256, 256, 0, stream>>>(proto_pre, an_b2, gcnt, counts_f,
                                                      headf, headi, fi);
    k_fuse_gemm<<<dim3(16, 65, 1), 256, 0, stream>>>(fi, 4160, 0, fu_w1, 0,
                                                     h1pre, 0, nullptr, 4100,
                                                     0, nullptr, nullptr, nullptr, nullptr,
                                                     nullptr, nullptr, nullptr);
    k_fuse_gemm<<<dim3(16, 16, 1), 256, 0, stream>>>(h1pre, 1024, 0, fu_w2, 0,
                                                     f2pre, 0, fu_b1, 1024,
                                                     0, nullptr, nullptr, nullptr, nullptr,
                                                     nullptr, nullptr, nullptr);
    k_final<<<NCLS * DIM / 256, 256, 0, stream>>>(f2pre, fu_b2, headi, rawsum, counts_f, dout);
}

// Round 15
// 307.460 us; speedup vs baseline: 1.0782x; 1.0782x over previous
//
#include <hip/hip_runtime.h>
#include <hip/hip_bf16.h>
#include <stdint.h>

#define N_SUP 16384
#define DIM   1024
#define NLV   4
#define NCLS  64
#define NFUSE 4096          // 4 levels x 1024

typedef __bf16 bf16x8 __attribute__((ext_vector_type(8)));
typedef __bf16 bf16x4 __attribute__((ext_vector_type(4)));
typedef float  f32x4  __attribute__((ext_vector_type(4)));

#define GLOAD_LDS16(g, l) \
    __builtin_amdgcn_global_load_lds((const __attribute__((address_space(1))) void*)(g), \
                                     (__attribute__((address_space(3))) void*)(l), 16, 0, 0)

// ---- class histogram, LDS-aggregated ----
__global__ __launch_bounds__(256) void k_count(const int* __restrict__ labels,
                                               int* __restrict__ gcnt) {
    __shared__ int hist[NCLS];
    int tid = threadIdx.x;
    if (tid < NCLS) hist[tid] = 0;
    __syncthreads();
    atomicAdd(&hist[labels[blockIdx.x * 256 + tid]], 1);
    __syncthreads();
    if (tid < NCLS && hist[tid] > 0) atomicAdd(&gcnt[tid], hist[tid]);
}

// ---- tiny scan: gstart, gcur, counts_f ----
__global__ __launch_bounds__(64) void k_scan(const int* __restrict__ gcnt,
                                             int* __restrict__ gstart,
                                             int* __restrict__ gcur,
                                             float* __restrict__ counts_f) {
    int tid = threadIdx.x;
    __shared__ int s[NCLS];
    s[tid] = gcnt[tid];
    __syncthreads();
    if (tid == 0) {
        int run = 0;
        for (int c = 0; c < NCLS; ++c) { int v = s[c]; s[c] = run; run += v; }
    }
    __syncthreads();
    gstart[tid] = s[tid];
    gcur[tid] = s[tid];
    counts_f[tid] = fmaxf((float)gcnt[tid], 1.0f);
}

// ---- scatter, LDS-aggregated; emits inv AND rowlist ----
__global__ __launch_bounds__(256) void k_scatter(const int* __restrict__ labels,
                                                 int* __restrict__ gcur,
                                                 int* __restrict__ inv,
                                                 int* __restrict__ rowlist) {
    __shared__ int hist[NCLS];
    __shared__ int base[NCLS];
    int tid = threadIdx.x;
    int r = blockIdx.x * 256 + tid;
    if (tid < NCLS) hist[tid] = 0;
    __syncthreads();
    int lab = labels[r];
    int lrank = atomicAdd(&hist[lab], 1);
    __syncthreads();
    if (tid < NCLS && hist[tid] > 0) base[tid] = atomicAdd(&gcur[tid], hist[tid]);
    __syncthreads();
    int pos = base[lab] + lrank;
    inv[r] = pos;
    rowlist[pos] = r;
}

// ==== mega prep dispatch: conv_feat (16384) | wt+eff (1024) | rawsum gather (256) ====
__global__ __launch_bounds__(256) void k_prep(const float* __restrict__ feat,
                                              const int* __restrict__ inv,
                                              const int* __restrict__ rowlist,
                                              const float* __restrict__ an_w1,
                                              const float* __restrict__ an_b1,
                                              const float* __restrict__ lvl_emb,
                                              const int* __restrict__ gstart,
                                              const int* __restrict__ gcnt,
                                              __bf16* __restrict__ featb,
                                              __bf16* __restrict__ w1t,
                                              float* __restrict__ eff,
                                              float* __restrict__ rawsum,
                                              float* __restrict__ tcsum) {
    __shared__ float tile[64][65];
    const int lin = blockIdx.x;
    const int tid = threadIdx.x;
    if (lin < 16384) {
        int r = lin;
        int dr = inv[r];
        float4 v = *(const float4*)(feat + (size_t)r * DIM + tid * 4);
        union { __bf16 b[4]; uint64_t u; } pk;
        pk.b[0] = (__bf16)v.x; pk.b[1] = (__bf16)v.y;
        pk.b[2] = (__bf16)v.z; pk.b[3] = (__bf16)v.w;
        *(uint64_t*)(featb + (size_t)dr * DIM + tid * 4) = pk.u;
    } else if (lin < 16384 + 1024) {
        int idx = lin - 16384;
        int m = idx >> 8;
        int rem = idx & 255;
        int k0 = (rem & 15) * 64, n0 = (rem >> 4) * 64;
        const float* src = an_w1 + (size_t)m * 1025 * 1024;
        __bf16* dst = w1t + (size_t)m * 1024 * 1024;
        int j = tid & 63, i0 = tid >> 6;
        #pragma unroll
        for (int ii = 0; ii < 16; ++ii) {
            int i = i0 + ii * 4;
            tile[i][j] = src[(size_t)(k0 + i) * 1024 + n0 + j];
        }
        __syncthreads();
        #pragma unroll
        for (int ii = 0; ii < 16; ++ii) {
            int i = i0 + ii * 4;
            dst[(size_t)(n0 + i) * 1024 + k0 + j] = (__bf16)tile[j][i];
        }
        if ((rem >> 4) == 0 && tid < 64) {
            int jj = k0 + tid;
            eff[m * 1024 + jj] = an_b1[m * 1024 + jj]
                               + lvl_emb[m] * src[(size_t)1024 * 1024 + jj];
        }
    } else {
        int idx = lin - 17408;
        int c = idx >> 2;
        int col = (idx & 3) * 256 + tid;
        int st = gstart[c], n = gcnt[c];
        float acc = 0.f;
        int i = 0;
        for (; i + 8 <= n; i += 8) {
            int r[8];
            #pragma unroll
            for (int j = 0; j < 8; ++j) r[j] = rowlist[st + i + j];
            float v[8];
            #pragma unroll
            for (int j = 0; j < 8; ++j) v[j] = feat[(size_t)r[j] * DIM + col];
            #pragma unroll
            for (int j = 0; j < 8; ++j) acc += v[j];
        }
        for (; i < n; ++i) acc += feat[(size_t)rowlist[st + i] * DIM + col];
        rawsum[(size_t)c * DIM + col] = acc;
        atomicAdd(&tcsum[col], acc);
    }
}

__global__ __launch_bounds__(512) void k_gemv1(const float* __restrict__ tc,
                                               const float* __restrict__ sp_w1,
                                               float* __restrict__ hpre) {
    __shared__ float tcs[64];
    int tid = threadIdx.x;
    int kb = blockIdx.x * 64;
    if (tid < 64) tcs[tid] = tc[kb + tid] * (1.0f / N_SUP);
    __syncthreads();
    float acc = 0.f;
    #pragma unroll 8
    for (int k = 0; k < 64; ++k)
        acc += tcs[k] * sp_w1[(size_t)(kb + k) * 512 + tid];
    atomicAdd(&hpre[tid], acc);
}

// ==================== 256x256 balanced 4-phase bf16 MFMA GEMM (R13/R9 core) ====
__global__ __launch_bounds__(512, 2) void k_gemm256(const __bf16* __restrict__ A,
                                                    const __bf16* __restrict__ Bt,
                                                    const float* __restrict__ bias,
                                                    __bf16* __restrict__ C,
                                                    int K, int Nn, int NT) {
    __shared__ __bf16 lds[65536];   // [buf][A|B][half][2 x 64rows][64]
    const int tid = threadIdx.x;
    const int w   = tid >> 6;
    const int l   = tid & 63;
    const int wr  = w >> 2;
    const int wc  = w & 3;
    const int am  = l & 15;
    const int kg  = l >> 4;
    const size_t bm = (size_t)blockIdx.x * 256;
    const size_t bn = (size_t)blockIdx.y * 256;

    const int srow = w * 8 + (l >> 3);
    const int scol = ((l & 7) ^ (l >> 3)) * 8;     // pre-swizzled source col
    const __bf16* gA[2][2]; const __bf16* gB[2][2];
    #pragma unroll
    for (int h = 0; h < 2; ++h)
        #pragma unroll
        for (int p = 0; p < 2; ++p) {
            gA[h][p] = A  + (bm + h * 128 + p * 64 + srow) * (size_t)K + scol;
            gB[h][p] = Bt + (bn + h * 128 + p * 64 + srow) * (size_t)K + scol;
        }

    f32x4 acc[8][4] = {};
    bf16x8 ax[4][2], ay[4][2], bx[2][2], by[2][2];

    // prologue: stage tile 0 (8 chunks), drain, read ax(0)
    #pragma unroll
    for (int h = 0; h < 2; ++h)
        #pragma unroll
        for (int p = 0; p < 2; ++p) {
            GLOAD_LDS16(gA[h][p], lds + h * 8192 + p * 4096 + w * 512);
            GLOAD_LDS16(gB[h][p], lds + 16384 + h * 8192 + p * 4096 + w * 512);
        }
    asm volatile("s_waitcnt vmcnt(0)" ::: "memory");
    __builtin_amdgcn_s_barrier();

    const int swzr = (am & 7) * 8;
    const int ko0 = (kg * 8) ^ swzr;
    const int ko1 = (32 + kg * 8) ^ swzr;
    {
        const __bf16* pa0 = lds + wr * 8192;
        #pragma unroll
        for (int i = 0; i < 4; ++i) {
            ax[i][0] = *(const bf16x8*)(pa0 + (i * 16 + am) * 64 + ko0);
            ax[i][1] = *(const bf16x8*)(pa0 + (i * 16 + am) * 64 + ko1);
        }
    }

#define MFMAQ(qm, qn, AF, BF) \
    __builtin_amdgcn_s_setprio(1); \
    _Pragma("unroll") \
    for (int i_ = 0; i_ < 4; ++i_) \
        _Pragma("unroll") \
        for (int j_ = 0; j_ < 2; ++j_) \
            _Pragma("unroll") \
            for (int k_ = 0; k_ < 2; ++k_) \
                acc[(qm) * 4 + i_][(qn) * 2 + j_] = __builtin_amdgcn_mfma_f32_16x16x32_bf16( \
                    AF[i_][k_], BF[j_][k_], acc[(qm) * 4 + i_][(qn) * 2 + j_], 0, 0, 0); \
    __builtin_amdgcn_s_setprio(0);

    for (int t = 0; t < NT; ++t) {
        const int cb = (t & 1) * 32768;
        const int nb = cb ^ 32768;
        const int tn = (t + 1) * 64;
        const bool more = (t + 1 < NT);
        const __bf16* pa  = lds + cb + wr * 8192;
        const __bf16* pan = lds + nb + wr * 8192;
        const __bf16* pb  = lds + cb + 16384 + (wc >> 1) * 8192 + (wc & 1) * 4096;

        // ---- ph0: issue Ap0(t+1); drain tile t; read bx(4)+ay0(2); MFMA q0 ----
        if (more) {
            GLOAD_LDS16(gA[0][0] + tn, lds + nb + 0 * 4096 + w * 512);
            GLOAD_LDS16(gA[1][0] + tn, lds + nb + 8192 + 0 * 4096 + w * 512);
            asm volatile("s_waitcnt vmcnt(2)" ::: "memory");
        } else {
            asm volatile("s_waitcnt vmcnt(0)" ::: "memory");
        }
        __builtin_amdgcn_s_barrier();
        #pragma unroll
        for (int j = 0; j < 2; ++j) {
            bx[j][0] = *(const bf16x8*)(pb + (j * 16 + am) * 64 + ko0);
            bx[j][1] = *(const bf16x8*)(pb + (j * 16 + am) * 64 + ko1);
        }
        ay[0][0] = *(const bf16x8*)(pa + ((4 + 0) * 16 + am) * 64 + ko0);
        ay[0][1] = *(const bf16x8*)(pa + ((4 + 0) * 16 + am) * 64 + ko1);
        MFMAQ(0, 0, ax, bx)

        // ---- ph1: issue Ap1(t+1); read by(4)+ay1(2); MFMA q1 ----
        if (more) {
            GLOAD_LDS16(gA[0][1] + tn, lds + nb + 1 * 4096 + w * 512);
            GLOAD_LDS16(gA[1][1] + tn, lds + nb + 8192 + 1 * 4096 + w * 512);
        }
        __builtin_amdgcn_s_barrier();
        #pragma unroll
        for (int j = 0; j < 2; ++j) {
            by[j][0] = *(const bf16x8*)(pb + ((2 + j) * 16 + am) * 64 + ko0);
            by[j][1] = *(const bf16x8*)(pb + ((2 + j) * 16 + am) * 64 + ko1);
        }
        ay[1][0] = *(const bf16x8*)(pa + ((4 + 1) * 16 + am) * 64 + ko0);
        ay[1][1] = *(const bf16x8*)(pa + ((4 + 1) * 16 + am) * 64 + ko1);
        MFMAQ(0, 1, ax, by)

        // ---- ph2: issue B0(t+1); drain Ap0(t+1); read ay23(4)+ax'01(4); MFMA q2 ----
        if (more) {
            GLOAD_LDS16(gB[0][0] + tn, lds + nb + 16384 + 0 * 4096 + w * 512);
            GLOAD_LDS16(gB[0][1] + tn, lds + nb + 16384 + 1 * 4096 + w * 512);
            asm volatile("s_waitcnt vmcnt(4)" ::: "memory");
        }
        __builtin_amdgcn_s_barrier();
        #pragma unroll
        for (int i = 2; i < 4; ++i) {
            ay[i][0] = *(const bf16x8*)(pa + ((4 + i) * 16 + am) * 64 + ko0);
            ay[i][1] = *(const bf16x8*)(pa + ((4 + i) * 16 + am) * 64 + ko1);
        }
        if (more) {
            #pragma unroll
            for (int i = 0; i < 2; ++i) {
                ax[i][0] = *(const bf16x8*)(pan + (i * 16 + am) * 64 + ko0);
                ax[i][1] = *(const bf16x8*)(pan + (i * 16 + am) * 64 + ko1);
            }
        }
        MFMAQ(1, 0, ay, bx)

        // ---- ph3: issue B1(t+1); read ax'23(4); MFMA q3 ----
        if (more) {
            GLOAD_LDS16(gB[1][0] + tn, lds + nb + 16384 + 8192 + 0 * 4096 + w * 512);
            GLOAD_LDS16(gB[1][1] + tn, lds + nb + 16384 + 8192 + 1 * 4096 + w * 512);
        }
        __builtin_amdgcn_s_barrier();
        if (more) {
            #pragma unroll
            for (int i = 2; i < 4; ++i) {
                ax[i][0] = *(const bf16x8*)(pan + (i * 16 + am) * 64 + ko0);
                ax[i][1] = *(const bf16x8*)(pan + (i * 16 + am) * 64 + ko1);
            }
        }
        MFMAQ(1, 1, ay, by)
    }
#undef MFMAQ

    const int rbase = kg * 4;    // C/D: col=lane&15, row=(lane>>4)*4+reg
    #pragma unroll
    for (int m = 0; m < 8; ++m) {
        const size_t row = bm + wr * 128 + m * 16 + rbase;
        #pragma unroll
        for (int n = 0; n < 4; ++n) {
            const int col = (int)bn + wc * 64 + n * 16 + am;
            const float bv = bias[col];
            #pragma unroll
            for (int r = 0; r < 4; ++r)
                C[(row + r) * (size_t)Nn + col] = (__bf16)(acc[m][n][r] + bv);
        }
    }
}

// ===== fused LN+ReLU+segment-sum, wave-per-row over SORTED hh =====
__global__ __launch_bounds__(256) void k_gather_ln(const __bf16* __restrict__ hh,
                                                   const float* __restrict__ an_g,
                                                   const float* __restrict__ an_be,
                                                   const int* __restrict__ gstart,
                                                   const int* __restrict__ gcnt,
                                                   float* __restrict__ gsum) {
    int c = blockIdx.x, lv = blockIdx.y, z = blockIdx.z;
    int tid = threadIdx.x;
    int wv = tid >> 6, lane = tid & 63;
    int colb = lane * 16;
    float g[16], b[16];
    #pragma unroll
    for (int j = 0; j < 16; j += 4) {
        float4 gv = *(const float4*)(an_g + lv * 1024 + colb + j);
        float4 bv = *(const float4*)(an_be + lv * 1024 + colb + j);
        g[j] = gv.x; g[j + 1] = gv.y; g[j + 2] = gv.z; g[j + 3] = gv.w;
        b[j] = bv.x; b[j + 1] = bv.y; b[j + 2] = bv.z; b[j + 3] = bv.w;
    }
    int st = gstart[c], n = gcnt[c];
    float acc[16] = {};
    for (int i = z * 4 + wv; i < n; i += 16) {
        const __bf16* row = hh + (size_t)(st + i) * NFUSE + lv * 1024 + colb;
        bf16x8 v0 = *(const bf16x8*)row;
        bf16x8 v1 = *(const bf16x8*)(row + 8);
        float x[16];
        #pragma unroll
        for (int j = 0; j < 8; ++j) { x[j] = (float)v0[j]; x[8 + j] = (float)v1[j]; }
        float s = 0.f, q = 0.f;
        #pragma unroll
        for (int j = 0; j < 16; ++j) { s += x[j]; q += x[j] * x[j]; }
        #pragma unroll
        for (int off = 1; off < 64; off <<= 1) {
            s += __shfl_xor(s, off);
            q += __shfl_xor(q, off);
        }
        float mu = s * (1.0f / DIM);
        float var = q * (1.0f / DIM) - mu * mu;
        float rstd = rsqrtf(var + 1e-5f);
        #pragma unroll
        for (int j = 0; j < 16; ++j) {
            float y = (x[j] - mu) * rstd * g[j] + b[j];
            acc[j] += y > 0.f ? y : 0.f;
        }
    }
    __shared__ float red[4][1024];
    #pragma unroll
    for (int j = 0; j < 16; ++j) red[wv][colb + j] = acc[j];
    __syncthreads();
    for (int col = tid; col < 1024; col += 256) {
        float v = red[0][col] + red[1][col] + red[2][col] + red[3][col];
        atomicAdd(&gsum[(size_t)c * NFUSE + lv * 1024 + col], v);
    }
}

// fusion_input build: packed part = proto_pre[l][c][d]/cnt[c] + b2[l][d]
__global__ __launch_bounds__(256) void k_build_fi(const float* __restrict__ proto_pre,
                                                  const float* __restrict__ an_b2,
                                                  const int* __restrict__ gcnt,
                                                  const float* __restrict__ counts_f,
                                                  const float* __restrict__ headf,
                                                  const int* __restrict__ headi,
                                                  float* __restrict__ fi) {
    int idx = blockIdx.x * 256 + threadIdx.x;
    if (idx >= 64 * 4160) return;
    int c = idx / 4160, col = idx % 4160;
    int kk = headi[0];
    float v = 0.f;
    if (col < kk * 1024) {
        int s = col >> 10, d = col & 1023;
        int l = headi[1 + s];
        if (gcnt[c] > 0)
            v = proto_pre[((size_t)l * NCLS + c) * DIM + d] / counts_f[c]
                + an_b2[(size_t)l * DIM + d];
    } else if (col < kk * 1024 + kk) {
        int s = col - kk * 1024;
        v = headf[headi[1 + s]];
    }
    fi[idx] = v;
}

// f32 split-K GEMM (64 x 1024 out), z-strided, atomic accumulate.
// abias != null: A element transformed as relu(a + abias[k]).
// do_head: block (0,0,4) runs the head finisher.
__global__ __launch_bounds__(256) void k_fuse_gemm(const float* __restrict__ Abase, int lda, int az,
                                                   const float* __restrict__ Wbase, int wz,
                                                   float* __restrict__ outbase, int oz,
                                                   const float* __restrict__ abias,
                                                   int K, int do_head,
                                                   const float* __restrict__ hpre,
                                                   const float* __restrict__ sp_b1,
                                                   const float* __restrict__ sp_w2,
                                                   const float* __restrict__ sp_b2,
                                                   float* __restrict__ headf,
                                                   int* __restrict__ headi,
                                                   float* __restrict__ dout) {
    if (do_head && blockIdx.z == 4) {
        if (blockIdx.x != 0 || blockIdx.y != 0) return;
        __shared__ float hred[256];
        __shared__ float ha4[4];
        int tid = threadIdx.x;
        float hv0 = hpre[tid] + sp_b1[tid];
        hv0 = hv0 > 0.f ? hv0 : 0.f;
        float hv1 = hpre[tid + 256] + sp_b1[tid + 256];
        hv1 = hv1 > 0.f ? hv1 : 0.f;
        #pragma unroll
        for (int o = 0; o < 4; ++o) {
            hred[tid] = hv0 * sp_w2[tid * 4 + o] + hv1 * sp_w2[(tid + 256) * 4 + o];
            __syncthreads();
            for (int st = 128; st > 0; st >>= 1) {
                if (tid < st) hred[tid] += hred[tid + st];
                __syncthreads();
            }
            if (tid == 0) ha4[o] = 1.0f / (1.0f + expf(-(hred[0] + sp_b2[o])));
            __syncthreads();
        }
        if (tid == 0) {
            int kk = 0;
            int lvl[4] = {-1, -1, -1, -1};
            for (int l = 0; l < 4; ++l)
                if (ha4[l] > 0.1f) { lvl[kk] = l; kk++; }
            headi[0] = kk;
            for (int s = 0; s < 4; ++s) headi[1 + s] = lvl[s];
            for (int l = 0; l < 4; ++l) headf[l] = ha4[l];
        }
        if (tid < 4) {
            dout[65536 + tid] = ha4[tid];
            dout[65540 + tid] = ha4[tid] > 0.1f ? ha4[tid] : 0.f;
        }
        return;
    }
    const float* Afi = Abase + (size_t)blockIdx.z * az;
    const float* W   = Wbase + (size_t)blockIdx.z * wz;
    float* outp      = outbase + (size_t)blockIdx.z * oz;
    __shared__ float fi_lds[64][64];
    int tid = threadIdx.x;
    int tj = tid & 63, tg = tid >> 6;
    int jb = blockIdx.x;
    int k0 = blockIdx.y * 64;
    for (int i = tid; i < 64 * 64; i += 256) {
        int cc = i >> 6, kq = i & 63;
        float av = 0.f;
        if (k0 + kq < lda) {
            av = Afi[(size_t)cc * lda + k0 + kq];
            if (abias) {
                av += abias[k0 + kq];
                av = av > 0.f ? av : 0.f;
            }
        }
        fi_lds[cc][kq] = av;
    }
    __syncthreads();
    float acc[16] = {};
    #pragma unroll 4
    for (int kq = 0; kq < 64; ++kq) {
        int kg = k0 + kq;
        float wv = (kg < K) ? W[(size_t)kg * 1024 + jb * 64 + tj] : 0.f;
        #pragma unroll
        for (int cc = 0; cc < 16; ++cc)
            acc[cc] += fi_lds[tg * 16 + cc][kq] * wv;
    }
    #pragma unroll
    for (int cc = 0; cc < 16; ++cc)
        atomicAdd(&outp[(size_t)(tg * 16 + cc) * 1024 + jb * 64 + tj], acc[cc]);
}

__global__ __launch_bounds__(256) void k_final(const float* __restrict__ pre2,
                                               const float* __restrict__ fu_b2,
                                               const int* __restrict__ headi,
                                               const float* __restrict__ rawsum,
                                               const float* __restrict__ counts_f,
                                               float* __restrict__ dout) {
    int i = blockIdx.x * 256 + threadIdx.x;   // 65536
    int c = i >> 10, j = i & 1023;
    float v;
    if (headi[0] > 0) v = pre2[i] + fu_b2[j];
    else              v = rawsum[i] / counts_f[c];
    dout[i] = v;
}

extern "C" void kernel_launch(void* const* d_in, const int* in_sizes, int n_in,
                              void* d_out, int out_size, void* d_ws, size_t ws_size,
                              hipStream_t stream) {
    (void)in_sizes; (void)n_in; (void)out_size; (void)ws_size;
    const float* feat    = (const float*)d_in[0];
    const int*   labels  = (const int*)d_in[1];
    const float* sp_w1   = (const float*)d_in[2];
    const float* sp_b1   = (const float*)d_in[3];
    const float* sp_w2   = (const float*)d_in[4];
    const float* sp_b2   = (const float*)d_in[5];
    const float* lvl_emb = (const float*)d_in[6];
    const float* an_w1   = (const float*)d_in[7];
    const float* an_b1   = (const float*)d_in[8];
    const float* an_g    = (const float*)d_in[9];
    const float* an_be   = (const float*)d_in[10];
    const float* an_w2   = (const float*)d_in[11];
    const float* an_b2   = (const float*)d_in[12];
    const float* fu_w1   = (const float*)d_in[13];
    const float* fu_b1   = (const float*)d_in[14];
    const float* fu_w2   = (const float*)d_in[15];
    const float* fu_b2   = (const float*)d_in[16];
    float* dout = (float*)d_out;

    char* p = (char*)d_ws;
    auto alloc = [&](size_t b) { char* r = p; p += (b + 255) & ~(size_t)255; return r; };
    __bf16* featb = (__bf16*)alloc((size_t)N_SUP * DIM * 2);
    __bf16* w1t   = (__bf16*)alloc((size_t)NLV * DIM * DIM * 2);
    __bf16* hh    = (__bf16*)alloc((size_t)N_SUP * NFUSE * 2);
    float*  effb1 = (float*) alloc((size_t)NLV * DIM * 4);
    float*  fi    = (float*) alloc((size_t)64 * 4160 * 4);
    float*  rawsum  = (float*)alloc((size_t)NCLS * DIM * 4);
    int*    inv     = (int*)  alloc((size_t)N_SUP * 4);
    int*    rowlist = (int*)  alloc((size_t)N_SUP * 4);
    int*    gstart  = (int*)  alloc(NCLS * 4);
    int*    gcur    = (int*)  alloc(NCLS * 4);
    float*  counts_f= (float*)alloc(NCLS * 4);
    float*  headf   = (float*)alloc(4 * 4);
    int*    headi   = (int*)  alloc(8 * 4);
    char* z0 = p;
    int*    gcnt    = (int*)  alloc(NCLS * 4);
    float*  tc      = (float*)alloc(DIM * 4);
    float*  gsum    = (float*)alloc((size_t)NCLS * NFUSE * 4);
    float*  proto_pre = (float*)alloc((size_t)NLV * NCLS * DIM * 4);
    float*  h1pre   = (float*)alloc((size_t)NCLS * DIM * 4);
    float*  f2pre   = (float*)alloc((size_t)NCLS * DIM * 4);
    float*  hpre    = (float*)alloc(512 * 4);
    size_t zbytes = (size_t)(p - z0);
    hipMemsetAsync(z0, 0, zbytes, stream);

    k_count<<<N_SUP / 256, 256, 0, stream>>>(labels, gcnt);
    k_scan<<<1, 64, 0, stream>>>(gcnt, gstart, gcur, counts_f);
    k_scatter<<<N_SUP / 256, 256, 0, stream>>>(labels, gcur, inv, rowlist);
    // mega prep: conv (16384) | wt+eff (1024) | rawsum gather (256)
    k_prep<<<16384 + 1024 + 256, 256, 0, stream>>>(feat, inv, rowlist, an_w1, an_b1,
                                                   lvl_emb, gstart, gcnt,
                                                   featb, w1t, effb1, rawsum, tc);
    k_gemv1<<<16, 512, 0, stream>>>(tc, sp_w1, hpre);
    // fused 4-level GEMM1 (pure, R13 codegen)
    k_gemm256<<<dim3(64, 16), 512, 0, stream>>>(featb, w1t, effb1, hh, DIM, NFUSE, DIM / 64);
    // fused LN+ReLU+segment-sum (contiguous class ranges)
    k_gather_ln<<<dim3(NCLS, NLV, 4), 256, 0, stream>>>(hh, an_g, an_be, gstart, gcnt, gsum);
    // proto_pre[l] = gsum[:, l*1024:+1024] @ an_w2[l]; z==4 runs head finisher
    k_fuse_gemm<<<dim3(16, 16, 5), 256, 0, stream>>>(gsum, NFUSE, 1024,
                                                     an_w2, 1024 * 1024,
                                                     proto_pre, NCLS * DIM, nullptr, 1024,
                                                     1, hpre, sp_b1, sp_w2, sp_b2,
                                                     headf, headi, dout);
    k_build_fi<<<(64 * 4160) / 256, 256, 0, stream>>>(proto_pre, an_b2, gcnt, counts_f,
                                                      headf, headi, fi);
    k_fuse_gemm<<<dim3(16, 65, 1), 256, 0, stream>>>(fi, 4160, 0, fu_w1, 0,
                                                     h1pre, 0, nullptr, 4100,
                                                     0, nullptr, nullptr, nullptr, nullptr,
                                                     nullptr, nullptr, nullptr);
    k_fuse_gemm<<<dim3(16, 16, 1), 256, 0, stream>>>(h1pre, 1024, 0, fu_w2, 0,
                                                     f2pre, 0, fu_b1, 1024,
                                                     0, nullptr, nullptr, nullptr, nullptr,
                                                     nullptr, nullptr, nullptr);
    k_final<<<NCLS * DIM / 256, 256, 0, stream>>>(f2pre, fu_b2, headi, rawsum, counts_f, dout);
}